// Round 5
// baseline (616.498 us; speedup 1.0000x reference)
//
#include <hip/hip_runtime.h>
#include <hip/hip_fp16.h>

#define N_NODES 50000
#define N_EDGES 800000
#define WIN_BITS 9
#define WIN 512
#define NBUK ((N_NODES + WIN - 1) / WIN)   // 98
#define BCAP 16384

// ---------------------------------------------------------------------------
// P0: bucket edges by destination window. Packed entry: (src << 9) | (dst & 511)
// ---------------------------------------------------------------------------
__global__ __launch_bounds__(256) void p0_bucket(const int* __restrict__ ei,
                                                 int* __restrict__ gcur,
                                                 unsigned* __restrict__ arena, int E) {
    __shared__ int lcnt[NBUK];
    __shared__ int lbase[NBUK];
    int tid = threadIdx.x;
    int chunk = (E + gridDim.x - 1) / gridDim.x;
    int e0 = blockIdx.x * chunk;
    int e1 = e0 + chunk; if (e1 > E) e1 = E;
    for (int b = tid; b < NBUK; b += 256) lcnt[b] = 0;
    __syncthreads();
    for (int e = e0 + tid; e < e1; e += 256) {
        int dst = ei[E + e];
        atomicAdd(&lcnt[dst >> WIN_BITS], 1);
    }
    __syncthreads();
    for (int b = tid; b < NBUK; b += 256) {
        lbase[b] = atomicAdd(&gcur[b], lcnt[b]);
        lcnt[b] = 0;
    }
    __syncthreads();
    for (int e = e0 + tid; e < e1; e += 256) {
        int dst = ei[E + e];
        int src = ei[e];
        int b = dst >> WIN_BITS;
        int pos = lbase[b] + atomicAdd(&lcnt[b], 1);
        if (pos < BCAP)
            arena[(size_t)b * BCAP + pos] = ((unsigned)src << WIN_BITS) | (unsigned)(dst & (WIN - 1));
    }
}

// ---------------------------------------------------------------------------
// P1: per-bucket degree count (LDS histogram) + dinv.
// ---------------------------------------------------------------------------
__global__ __launch_bounds__(256) void p1_count(const unsigned* __restrict__ arena,
                                                const int* __restrict__ gcur,
                                                int* __restrict__ deg,
                                                float* __restrict__ dinv, int n) {
    __shared__ int cnt[WIN];
    int b = blockIdx.x, tid = threadIdx.x;
    for (int j = tid; j < WIN; j += 256) cnt[j] = 0;
    __syncthreads();
    int m = gcur[b]; if (m > BCAP) m = BCAP;
    const unsigned* a = arena + (size_t)b * BCAP;
    for (int i = tid; i < m; i += 256) atomicAdd(&cnt[a[i] & (WIN - 1)], 1);
    __syncthreads();
    int base = b << WIN_BITS;
    for (int j = tid; j < WIN; j += 256) {
        int d = base + j;
        if (d < n) {
            int c = cnt[j];
            deg[d] = c;
            dinv[d] = rsqrtf((float)(c + 1));
        }
    }
}

// ---------------------------------------------------------------------------
// Scan (3-phase)
// ---------------------------------------------------------------------------
__global__ __launch_bounds__(256) void scan_blocksum(const int* __restrict__ deg,
                                                     int* __restrict__ blocksum, int n) {
    int tid = threadIdx.x;
    int i0 = blockIdx.x * 1024 + tid * 4;
    int4 d = make_int4(0, 0, 0, 0);
    if (i0 + 3 < n) d = *(const int4*)&deg[i0];
    else {
        if (i0 < n)     d.x = deg[i0];
        if (i0 + 1 < n) d.y = deg[i0 + 1];
        if (i0 + 2 < n) d.z = deg[i0 + 2];
        if (i0 + 3 < n) d.w = deg[i0 + 3];
    }
    int s = d.x + d.y + d.z + d.w;
    #pragma unroll
    for (int off = 1; off < 64; off <<= 1) s += __shfl_xor(s, off);
    __shared__ int ws[4];
    if ((tid & 63) == 0) ws[tid >> 6] = s;
    __syncthreads();
    if (tid == 0) blocksum[blockIdx.x] = ws[0] + ws[1] + ws[2] + ws[3];
}

__global__ void scan_blockoff(const int* __restrict__ blocksum, int* __restrict__ blockoff,
                              int nb, int* __restrict__ offsets, int n, int total) {
    int lane = threadIdx.x;
    int v = (lane < nb) ? blocksum[lane] : 0;
    int orig = v;
    #pragma unroll
    for (int off = 1; off < 64; off <<= 1) {
        int t = __shfl_up(v, off);
        if (lane >= off) v += t;
    }
    if (lane < nb) blockoff[lane] = v - orig;
    if (lane == 0) offsets[n] = total;
}

__global__ __launch_bounds__(256) void scan_fill(const int* __restrict__ deg,
                                                 const int* __restrict__ blockoff,
                                                 int* __restrict__ offsets, int n) {
    int tid = threadIdx.x;
    int i0 = blockIdx.x * 1024 + tid * 4;
    int4 d = make_int4(0, 0, 0, 0);
    if (i0 + 3 < n) d = *(const int4*)&deg[i0];
    else {
        if (i0 < n)     d.x = deg[i0];
        if (i0 + 1 < n) d.y = deg[i0 + 1];
        if (i0 + 2 < n) d.z = deg[i0 + 2];
        if (i0 + 3 < n) d.w = deg[i0 + 3];
    }
    int ts = d.x + d.y + d.z + d.w;
    __shared__ int sbuf[256];
    sbuf[tid] = ts;
    __syncthreads();
    #pragma unroll
    for (int off = 1; off < 256; off <<= 1) {
        int t = (tid >= off) ? sbuf[tid - off] : 0;
        __syncthreads();
        sbuf[tid] += t;
        __syncthreads();
    }
    int base = blockoff[blockIdx.x] + (sbuf[tid] - ts);
    int o0 = base, o1 = o0 + d.x, o2 = o1 + d.y, o3 = o2 + d.z;
    if (i0 + 3 < n) {
        *(int4*)&offsets[i0] = make_int4(o0, o1, o2, o3);
    } else {
        if (i0 < n)     offsets[i0]     = o0;
        if (i0 + 1 < n) offsets[i0 + 1] = o1;
        if (i0 + 2 < n) offsets[i0 + 2] = o2;
    }
}

// ---------------------------------------------------------------------------
// P2: per-bucket CSR fill.
// ---------------------------------------------------------------------------
__global__ __launch_bounds__(256) void p2_fill(const unsigned* __restrict__ arena,
                                               const int* __restrict__ gcur,
                                               const int* __restrict__ offsets,
                                               int* __restrict__ csr_src, int n) {
    __shared__ int cur[WIN];
    int b = blockIdx.x, tid = threadIdx.x;
    int base = b << WIN_BITS;
    for (int j = tid; j < WIN; j += 256) {
        int d = base + j;
        cur[j] = (d < n) ? offsets[d] : 0;
    }
    __syncthreads();
    int m = gcur[b]; if (m > BCAP) m = BCAP;
    const unsigned* a = arena + (size_t)b * BCAP;
    for (int i = tid; i < m; i += 256) {
        unsigned e = a[i];
        int pos = atomicAdd(&cur[e & (WIN - 1)], 1);
        csr_src[pos] = (int)(e >> WIN_BITS);
    }
}

// ---------------------------------------------------------------------------
// GEMM: h[i][j] = fp16( (x[i,:] @ W[:,j]) * dinv[i] ).  FI = 128.
// 64 rows/block (grid 782 -> ~3 blocks/CU), split-K LDS staging (2 x 64 rows,
// 32 KB for FO=128) to keep occupancy. Bank-swizzled W layout as before.
// ---------------------------------------------------------------------------
template<int FO>
__global__ __launch_bounds__((FO / 16) * 32) void gemm_scale_kernel(
        const float* __restrict__ x, const float* __restrict__ W,
        const float* __restrict__ dinv, __half* __restrict__ h, int n) {
    constexpr int TC      = FO / 16;     // 8 (FO=128) or 4 (FO=64)
    constexpr int THREADS = TC * 32;     // 256 or 128
    constexpr int F4      = FO / 4;      // float4s per W row

    __shared__ float w_lds[64 * FO];     // 32 KB / 16 KB (half-K stage)
    int tid = threadIdx.x;
    int tc = tid % TC, tr = tid / TC;    // tr in 0..31
    int j0 = tc * 16;
    int row0 = blockIdx.x * 64 + tr * 2;

    const float* xp[2];
    #pragma unroll
    for (int r = 0; r < 2; ++r) {
        int rowc = row0 + r; if (rowc > n - 1) rowc = n - 1;   // clamp: safe reads
        xp[r] = x + (size_t)rowc * 128;
    }

    float acc[2][16];
    #pragma unroll
    for (int r = 0; r < 2; ++r)
        #pragma unroll
        for (int c = 0; c < 16; ++c) acc[r][c] = 0.0f;

    #pragma unroll
    for (int stage = 0; stage < 2; ++stage) {
        int ks = stage << 6;
        if (stage) __syncthreads();
        // stage W rows [ks, ks+64) swizzled: src float4 jf4 -> slot (jf4&3)*TC + (jf4>>2)
        for (int i = tid; i < 64 * F4; i += THREADS) {
            int r = i / F4, jf4 = i % F4;
            int tcg = jf4 >> 2, qg = jf4 & 3;
            float4 v = *(const float4*)&W[(size_t)(ks + r) * FO + jf4 * 4];
            *(float4*)&w_lds[(size_t)r * FO + (qg * TC + tcg) * 4] = v;
        }
        __syncthreads();

        float4 xb[2];
        #pragma unroll
        for (int r = 0; r < 2; ++r) xb[r] = *(const float4*)&xp[r][ks];

        for (int kk = 0; kk < 64; kk += 4) {
            float4 xc[2];
            xc[0] = xb[0]; xc[1] = xb[1];
            if (kk + 4 < 64) {
                #pragma unroll
                for (int r = 0; r < 2; ++r) xb[r] = *(const float4*)&xp[r][ks + kk + 4];
            }
            #pragma unroll
            for (int dk = 0; dk < 4; ++dk) {
                float w[16];
                #pragma unroll
                for (int q = 0; q < 4; ++q)
                    *(float4*)&w[q * 4] = *(const float4*)&w_lds[(size_t)(kk + dk) * FO + (q * TC + tc) * 4];
                #pragma unroll
                for (int r = 0; r < 2; ++r) {
                    float xs = (&xc[r].x)[dk];
                    #pragma unroll
                    for (int c = 0; c < 16; ++c)
                        acc[r][c] = fmaf(xs, w[c], acc[r][c]);
                }
            }
        }
    }

    #pragma unroll
    for (int r = 0; r < 2; ++r) {
        int row = row0 + r;
        if (row < n) {
            float d = dinv[row];
            __half2 hv[8];
            #pragma unroll
            for (int q = 0; q < 8; ++q)
                hv[q] = __float22half2_rn(make_float2(acc[r][2 * q] * d, acc[r][2 * q + 1] * d));
            uint4* dst = (uint4*)&h[(size_t)row * FO + j0];
            const uint4* srcp = (const uint4*)hv;
            dst[0] = srcp[0];
            dst[1] = srcp[1];
        }
    }
}

// ---------------------------------------------------------------------------
// Chunked XCD-affine aggregation.
// 128-feature layers: 4 chunks x 32 features. Wave = 4 subgroups x 16 lanes;
// subgroup g gathers edge (s+g+4k)'s 64-B chunk; xor-shuffle reduce (16,32).
// chunk = (blockIdx&7)>>1 so (assuming %8 XCD round-robin) each XCD touches
// one 3.2 MB feature slice -> L2-resident gathers.
// ---------------------------------------------------------------------------
template<bool RELU>
__global__ __launch_bounds__(256) void agg128c_kernel(
        const __half2* __restrict__ h2, const int* __restrict__ offsets,
        const int* __restrict__ csr_src, const float* __restrict__ dinv,
        const float* __restrict__ bias, float* __restrict__ out, int n) {
    int lane = threadIdx.x & 63;
    int sub = lane >> 4;                 // 0..3
    int sl  = lane & 15;
    int q = blockIdx.x & 7;
    int r = blockIdx.x >> 3;
    int chunk = q >> 1;                  // 0..3
    int ng = r * 2 + (q & 1);            // node group
    int c = ng * 4 + (threadIdx.x >> 6);
    if (c >= n) return;
    c = __builtin_amdgcn_readfirstlane(c);
    int dw = chunk * 16 + sl;            // half2 index within row [0,64)

    float2 acc = make_float2(0.0f, 0.0f);
    if (sub == 0) acc = __half22float2(h2[(size_t)c * 64 + dw]);   // self loop

    int s = offsets[c], e = offsets[c + 1];
    for (int i = s + sub; i < e; i += 4) {
        int src = csr_src[i];
        float2 f = __half22float2(h2[(size_t)src * 64 + dw]);
        acc.x += f.x; acc.y += f.y;
    }
    acc.x += __shfl_xor(acc.x, 16); acc.y += __shfl_xor(acc.y, 16);
    acc.x += __shfl_xor(acc.x, 32); acc.y += __shfl_xor(acc.y, 32);

    if (sub == 0) {
        float dc = dinv[c];
        float2 bb = ((const float2*)bias)[dw];
        float vx = fmaf(acc.x, dc, bb.x);
        float vy = fmaf(acc.y, dc, bb.y);
        if (RELU) { vx = fmaxf(vx, 0.0f); vy = fmaxf(vy, 0.0f); }
        float2 o; o.x = vx; o.y = vy;
        ((float2*)out)[(size_t)c * 64 + dw] = o;
    }
}

// 64-feature final layer: 2 chunks x 32 features, same wave layout.
__global__ __launch_bounds__(256) void agg64c_kernel(
        const __half2* __restrict__ h2, const int* __restrict__ offsets,
        const int* __restrict__ csr_src, const float* __restrict__ dinv,
        const float* __restrict__ bias, float* __restrict__ out, int n) {
    int lane = threadIdx.x & 63;
    int sub = lane >> 4;
    int sl  = lane & 15;
    int q = blockIdx.x & 7;
    int r = blockIdx.x >> 3;
    int chunk = q >> 2;                  // 0..1
    int ng = r * 4 + (q & 3);
    int c = ng * 4 + (threadIdx.x >> 6);
    if (c >= n) return;
    c = __builtin_amdgcn_readfirstlane(c);
    int dw = chunk * 16 + sl;            // half2 index within row [0,32)

    float2 acc = make_float2(0.0f, 0.0f);
    if (sub == 0) acc = __half22float2(h2[(size_t)c * 32 + dw]);

    int s = offsets[c], e = offsets[c + 1];
    for (int i = s + sub; i < e; i += 4) {
        int src = csr_src[i];
        float2 f = __half22float2(h2[(size_t)src * 32 + dw]);
        acc.x += f.x; acc.y += f.y;
    }
    acc.x += __shfl_xor(acc.x, 16); acc.y += __shfl_xor(acc.y, 16);
    acc.x += __shfl_xor(acc.x, 32); acc.y += __shfl_xor(acc.y, 32);

    if (sub == 0) {
        float dc = dinv[c];
        float2 bb = ((const float2*)bias)[dw];
        float2 o;
        o.x = fmaf(acc.x, dc, bb.x);
        o.y = fmaf(acc.y, dc, bb.y);
        ((float2*)out)[(size_t)c * 32 + dw] = o;
    }
}

// ---------------------------------------------------------------------------

extern "C" void kernel_launch(void* const* d_in, const int* in_sizes, int n_in,
                              void* d_out, int out_size, void* d_ws, size_t ws_size,
                              hipStream_t stream) {
    const float* x  = (const float*)d_in[0];
    const int*   ei = (const int*)  d_in[1];
    const float* W1 = (const float*)d_in[2];
    const float* b1 = (const float*)d_in[3];
    const float* W2 = (const float*)d_in[4];
    const float* b2 = (const float*)d_in[5];
    const float* W3 = (const float*)d_in[6];
    const float* b3 = (const float*)d_in[7];
    const float* W4 = (const float*)d_in[8];
    const float* b4 = (const float*)d_in[9];

    const int N = N_NODES, E = N_EDGES;
    const int NSB = (N + 1023) / 1024;

    char* p = (char*)d_ws;
    auto carve = [&](size_t bytes) {
        char* q = p;
        p += (bytes + 255) & ~(size_t)255;
        return (void*)q;
    };
    int*      deg      = (int*)     carve((size_t)N * 4);
    int*      offsets  = (int*)     carve((size_t)(N + 1) * 4);
    int*      csr_src  = (int*)     carve((size_t)E * 4);
    float*    dinv     = (float*)   carve((size_t)N * 4);
    int*      blocksum = (int*)     carve((size_t)NSB * 4);
    int*      blockoff = (int*)     carve((size_t)NSB * 4);
    int*      gcur     = (int*)     carve((size_t)NBUK * 4);
    unsigned* arena    = (unsigned*)carve((size_t)NBUK * BCAP * 4);
    __half*   A        = (__half*)  carve((size_t)N * 128 * 2);   // fp16 GEMM out
    float*    B        = (float*)   carve((size_t)N * 128 * 4);   // fp32 agg out

    // ---- graph build ----
    hipMemsetAsync(gcur, 0, (size_t)NBUK * 4, stream);
    p0_bucket<<<512, 256, 0, stream>>>(ei, gcur, arena, E);
    p1_count<<<NBUK, 256, 0, stream>>>(arena, gcur, deg, dinv, N);
    scan_blocksum<<<NSB, 256, 0, stream>>>(deg, blocksum, N);
    scan_blockoff<<<1, 64, 0, stream>>>(blocksum, blockoff, NSB, offsets, N, E);
    scan_fill<<<NSB, 256, 0, stream>>>(deg, blockoff, offsets, N);
    p2_fill<<<NBUK, 256, 0, stream>>>(arena, gcur, offsets, csr_src, N);

    // ---- layers ----
    const int gemm_grid   = (N + 63) / 64;          // 782
    const int agg128_grid = ((N + 7) / 8) * 8;      // r in [0,6250) x 8 = 50000
    const int agg64_grid  = ((N + 15) / 16) * 8;    // r in [0,3125) x 8 = 25000

    gemm_scale_kernel<128><<<gemm_grid, 256, 0, stream>>>(x, W1, dinv, A, N);
    agg128c_kernel<true><<<agg128_grid, 256, 0, stream>>>((const __half2*)A, offsets, csr_src, dinv, b1, B, N);
    gemm_scale_kernel<128><<<gemm_grid, 256, 0, stream>>>(B, W2, dinv, A, N);
    agg128c_kernel<true><<<agg128_grid, 256, 0, stream>>>((const __half2*)A, offsets, csr_src, dinv, b2, B, N);
    gemm_scale_kernel<128><<<gemm_grid, 256, 0, stream>>>(B, W3, dinv, A, N);
    agg128c_kernel<true><<<agg128_grid, 256, 0, stream>>>((const __half2*)A, offsets, csr_src, dinv, b3, B, N);
    gemm_scale_kernel<64><<<gemm_grid, 128, 0, stream>>>(B, W4, dinv, A, N);
    agg64c_kernel<<<agg64_grid, 256, 0, stream>>>((const __half2*)A, offsets, csr_src, dinv, b4, (float*)d_out, N);
}

// Round 6
// 552.039 us; speedup vs baseline: 1.1168x; 1.1168x over previous
//
#include <hip/hip_runtime.h>
#include <hip/hip_fp16.h>

#define N_NODES 50000
#define N_EDGES 800000
#define WIN_BITS 9
#define WIN 512
#define NBUK ((N_NODES + WIN - 1) / WIN)   // 98
#define BCAP 16384

// ---------------------------------------------------------------------------
// P0: bucket edges by destination window. Packed entry: (src << 9) | (dst & 511)
// ---------------------------------------------------------------------------
__global__ __launch_bounds__(256) void p0_bucket(const int* __restrict__ ei,
                                                 int* __restrict__ gcur,
                                                 unsigned* __restrict__ arena, int E) {
    __shared__ int lcnt[NBUK];
    __shared__ int lbase[NBUK];
    int tid = threadIdx.x;
    int chunk = (E + gridDim.x - 1) / gridDim.x;
    int e0 = blockIdx.x * chunk;
    int e1 = e0 + chunk; if (e1 > E) e1 = E;
    for (int b = tid; b < NBUK; b += 256) lcnt[b] = 0;
    __syncthreads();
    for (int e = e0 + tid; e < e1; e += 256) {
        int dst = ei[E + e];
        atomicAdd(&lcnt[dst >> WIN_BITS], 1);
    }
    __syncthreads();
    for (int b = tid; b < NBUK; b += 256) {
        lbase[b] = atomicAdd(&gcur[b], lcnt[b]);
        lcnt[b] = 0;
    }
    __syncthreads();
    for (int e = e0 + tid; e < e1; e += 256) {
        int dst = ei[E + e];
        int src = ei[e];
        int b = dst >> WIN_BITS;
        int pos = lbase[b] + atomicAdd(&lcnt[b], 1);
        if (pos < BCAP)
            arena[(size_t)b * BCAP + pos] = ((unsigned)src << WIN_BITS) | (unsigned)(dst & (WIN - 1));
    }
}

// ---------------------------------------------------------------------------
// P1: per-bucket degree count (LDS histogram) + dinv.
// ---------------------------------------------------------------------------
__global__ __launch_bounds__(256) void p1_count(const unsigned* __restrict__ arena,
                                                const int* __restrict__ gcur,
                                                int* __restrict__ deg,
                                                float* __restrict__ dinv, int n) {
    __shared__ int cnt[WIN];
    int b = blockIdx.x, tid = threadIdx.x;
    for (int j = tid; j < WIN; j += 256) cnt[j] = 0;
    __syncthreads();
    int m = gcur[b]; if (m > BCAP) m = BCAP;
    const unsigned* a = arena + (size_t)b * BCAP;
    for (int i = tid; i < m; i += 256) atomicAdd(&cnt[a[i] & (WIN - 1)], 1);
    __syncthreads();
    int base = b << WIN_BITS;
    for (int j = tid; j < WIN; j += 256) {
        int d = base + j;
        if (d < n) {
            int c = cnt[j];
            deg[d] = c;
            dinv[d] = rsqrtf((float)(c + 1));
        }
    }
}

// ---------------------------------------------------------------------------
// Scan (3-phase)
// ---------------------------------------------------------------------------
__global__ __launch_bounds__(256) void scan_blocksum(const int* __restrict__ deg,
                                                     int* __restrict__ blocksum, int n) {
    int tid = threadIdx.x;
    int i0 = blockIdx.x * 1024 + tid * 4;
    int4 d = make_int4(0, 0, 0, 0);
    if (i0 + 3 < n) d = *(const int4*)&deg[i0];
    else {
        if (i0 < n)     d.x = deg[i0];
        if (i0 + 1 < n) d.y = deg[i0 + 1];
        if (i0 + 2 < n) d.z = deg[i0 + 2];
        if (i0 + 3 < n) d.w = deg[i0 + 3];
    }
    int s = d.x + d.y + d.z + d.w;
    #pragma unroll
    for (int off = 1; off < 64; off <<= 1) s += __shfl_xor(s, off);
    __shared__ int ws[4];
    if ((tid & 63) == 0) ws[tid >> 6] = s;
    __syncthreads();
    if (tid == 0) blocksum[blockIdx.x] = ws[0] + ws[1] + ws[2] + ws[3];
}

__global__ void scan_blockoff(const int* __restrict__ blocksum, int* __restrict__ blockoff,
                              int nb, int* __restrict__ offsets, int n, int total) {
    int lane = threadIdx.x;
    int v = (lane < nb) ? blocksum[lane] : 0;
    int orig = v;
    #pragma unroll
    for (int off = 1; off < 64; off <<= 1) {
        int t = __shfl_up(v, off);
        if (lane >= off) v += t;
    }
    if (lane < nb) blockoff[lane] = v - orig;
    if (lane == 0) offsets[n] = total;
}

__global__ __launch_bounds__(256) void scan_fill(const int* __restrict__ deg,
                                                 const int* __restrict__ blockoff,
                                                 int* __restrict__ offsets, int n) {
    int tid = threadIdx.x;
    int i0 = blockIdx.x * 1024 + tid * 4;
    int4 d = make_int4(0, 0, 0, 0);
    if (i0 + 3 < n) d = *(const int4*)&deg[i0];
    else {
        if (i0 < n)     d.x = deg[i0];
        if (i0 + 1 < n) d.y = deg[i0 + 1];
        if (i0 + 2 < n) d.z = deg[i0 + 2];
        if (i0 + 3 < n) d.w = deg[i0 + 3];
    }
    int ts = d.x + d.y + d.z + d.w;
    __shared__ int sbuf[256];
    sbuf[tid] = ts;
    __syncthreads();
    #pragma unroll
    for (int off = 1; off < 256; off <<= 1) {
        int t = (tid >= off) ? sbuf[tid - off] : 0;
        __syncthreads();
        sbuf[tid] += t;
        __syncthreads();
    }
    int base = blockoff[blockIdx.x] + (sbuf[tid] - ts);
    int o0 = base, o1 = o0 + d.x, o2 = o1 + d.y, o3 = o2 + d.z;
    if (i0 + 3 < n) {
        *(int4*)&offsets[i0] = make_int4(o0, o1, o2, o3);
    } else {
        if (i0 < n)     offsets[i0]     = o0;
        if (i0 + 1 < n) offsets[i0 + 1] = o1;
        if (i0 + 2 < n) offsets[i0 + 2] = o2;
    }
}

// ---------------------------------------------------------------------------
// P2: per-bucket CSR fill.
// ---------------------------------------------------------------------------
__global__ __launch_bounds__(256) void p2_fill(const unsigned* __restrict__ arena,
                                               const int* __restrict__ gcur,
                                               const int* __restrict__ offsets,
                                               int* __restrict__ csr_src, int n) {
    __shared__ int cur[WIN];
    int b = blockIdx.x, tid = threadIdx.x;
    int base = b << WIN_BITS;
    for (int j = tid; j < WIN; j += 256) {
        int d = base + j;
        cur[j] = (d < n) ? offsets[d] : 0;
    }
    __syncthreads();
    int m = gcur[b]; if (m > BCAP) m = BCAP;
    const unsigned* a = arena + (size_t)b * BCAP;
    for (int i = tid; i < m; i += 256) {
        unsigned e = a[i];
        int pos = atomicAdd(&cur[e & (WIN - 1)], 1);
        csr_src[pos] = (int)(e >> WIN_BITS);
    }
}

// ---------------------------------------------------------------------------
// GEMM: hc[chunk][i][j'] = fp16( (x[i,:] @ W[:,j]) * dinv[i] ), chunk-major out
// (chunk = j/32, 32 feats = 16 half2 per node-chunk row).
// Thread tile 4 rows x 8 cols; 64 rows/block -> grid 782 (~3 blocks/CU).
// Split-K LDS staging (64 k-rows, 32/16 KB). Slot swizzle: float4 slot s ->
// (s&1)*(F4/2) + (s>>1): the two per-thread ds_read_b128 are 2-way-conflict
// (free) instead of 4-way.
// ---------------------------------------------------------------------------
template<int FO>
__global__ __launch_bounds__(16 * (FO / 8)) void gemm_scale_kernel(
        const float* __restrict__ x, const float* __restrict__ W,
        const float* __restrict__ dinv, __half2* __restrict__ hc, int n) {
    constexpr int TC      = FO / 8;       // col groups: 16 (FO=128) / 8 (FO=64)
    constexpr int THREADS = TC * 16;      // 256 / 128
    constexpr int F4      = FO / 4;
    constexpr int HALF    = F4 / 2;

    __shared__ float w_lds[64 * FO];      // 32 KB / 16 KB
    int tid = threadIdx.x;
    int tc = tid % TC, tr = tid / TC;     // tr in [0,16)
    int row0 = blockIdx.x * 64 + tr * 4;

    const float* xp[4];
    #pragma unroll
    for (int r = 0; r < 4; ++r) {
        int rowc = row0 + r; if (rowc > n - 1) rowc = n - 1;   // clamp: safe reads
        xp[r] = x + (size_t)rowc * 128;
    }

    float acc[4][8];
    #pragma unroll
    for (int r = 0; r < 4; ++r)
        #pragma unroll
        for (int c = 0; c < 8; ++c) acc[r][c] = 0.0f;

    #pragma unroll
    for (int stage = 0; stage < 2; ++stage) {
        int ks = stage << 6;
        if (stage) __syncthreads();
        for (int i = tid; i < 64 * F4; i += THREADS) {
            int r = i / F4, jf4 = i % F4;
            int phys = (jf4 & 1) * HALF + (jf4 >> 1);
            float4 v = *(const float4*)&W[(size_t)(ks + r) * FO + jf4 * 4];
            *(float4*)&w_lds[(size_t)r * FO + phys * 4] = v;
        }
        __syncthreads();

        float4 xb[4];
        #pragma unroll
        for (int r = 0; r < 4; ++r) xb[r] = *(const float4*)&xp[r][ks];

        for (int kk = 0; kk < 64; kk += 4) {
            float4 xc[4];
            #pragma unroll
            for (int r = 0; r < 4; ++r) xc[r] = xb[r];
            if (kk + 4 < 64) {
                #pragma unroll
                for (int r = 0; r < 4; ++r) xb[r] = *(const float4*)&xp[r][ks + kk + 4];
            }
            #pragma unroll
            for (int dk = 0; dk < 4; ++dk) {
                float w[8];
                *(float4*)&w[0] = *(const float4*)&w_lds[(size_t)(kk + dk) * FO + tc * 4];
                *(float4*)&w[4] = *(const float4*)&w_lds[(size_t)(kk + dk) * FO + (HALF + tc) * 4];
                #pragma unroll
                for (int r = 0; r < 4; ++r) {
                    float xs = (&xc[r].x)[dk];
                    #pragma unroll
                    for (int c = 0; c < 8; ++c)
                        acc[r][c] = fmaf(xs, w[c], acc[r][c]);
                }
            }
        }
    }

    // epilogue: cols j0 = tc*8 -> chunk tc>>2, half2 offset (tc&3)*4
    int chunk = tc >> 2;
    int off = (tc & 3) * 4;
    __half2* base = hc + (size_t)chunk * n * 16;
    #pragma unroll
    for (int r = 0; r < 4; ++r) {
        int row = row0 + r;
        if (row < n) {
            float d = dinv[row];
            __half2 hv[4];
            #pragma unroll
            for (int q = 0; q < 4; ++q)
                hv[q] = __float22half2_rn(make_float2(acc[r][2 * q] * d, acc[r][2 * q + 1] * d));
            *(uint4*)&base[(size_t)row * 16 + off] = *(const uint4*)hv;
        }
    }
}

// ---------------------------------------------------------------------------
// Chunked aggregation, chunk-major h, chunk time-sliced via blockIdx.y.
// Wave = 4 subgroups x 16 lanes; subgroup g handles edges i ≡ g (mod 4),
// unrolled x4 -> 4 independent 64-B gathers in flight per wave.
// out[c][chunk*32 + f] = dinv[c]*(hc[chunk][c] + sum hc[chunk][src]) + b.
// ---------------------------------------------------------------------------
template<bool RELU, int OUTW>   // OUTW = float2 per out row (64 or 32)
__global__ __launch_bounds__(256) void agg_chunk_kernel(
        const __half2* __restrict__ hc, const int* __restrict__ offsets,
        const int* __restrict__ csr_src, const float* __restrict__ dinv,
        const float* __restrict__ bias, float* __restrict__ out, int n) {
    int lane = threadIdx.x & 63;
    int sub = lane >> 4, sl = lane & 15;
    int chunk = blockIdx.y;
    int c = blockIdx.x * 4 + (threadIdx.x >> 6);
    if (c >= n) return;                    // wave-uniform
    c = __builtin_amdgcn_readfirstlane(c);
    const __half2* base = hc + (size_t)chunk * n * 16;

    float2 acc = make_float2(0.0f, 0.0f);
    if (sub == 0) acc = __half22float2(base[(size_t)c * 16 + sl]);   // self loop

    int s = offsets[c], e = offsets[c + 1];
    int i = s + sub;
    for (; i + 12 < e; i += 16) {
        int s0 = csr_src[i], s1 = csr_src[i + 4], s2 = csr_src[i + 8], s3 = csr_src[i + 12];
        float2 f0 = __half22float2(base[(size_t)s0 * 16 + sl]);
        float2 f1 = __half22float2(base[(size_t)s1 * 16 + sl]);
        float2 f2 = __half22float2(base[(size_t)s2 * 16 + sl]);
        float2 f3 = __half22float2(base[(size_t)s3 * 16 + sl]);
        acc.x += f0.x + f1.x; acc.y += f0.y + f1.y;
        acc.x += f2.x + f3.x; acc.y += f2.y + f3.y;
    }
    for (; i < e; i += 4) {
        float2 f = __half22float2(base[(size_t)csr_src[i] * 16 + sl]);
        acc.x += f.x; acc.y += f.y;
    }
    acc.x += __shfl_xor(acc.x, 16); acc.y += __shfl_xor(acc.y, 16);
    acc.x += __shfl_xor(acc.x, 32); acc.y += __shfl_xor(acc.y, 32);

    if (sub == 0) {
        float dc = dinv[c];
        float2 bb = ((const float2*)bias)[chunk * 16 + sl];
        float vx = fmaf(acc.x, dc, bb.x);
        float vy = fmaf(acc.y, dc, bb.y);
        if (RELU) { vx = fmaxf(vx, 0.0f); vy = fmaxf(vy, 0.0f); }
        float2 o; o.x = vx; o.y = vy;
        ((float2*)out)[(size_t)c * OUTW + chunk * 16 + sl] = o;
    }
}

// ---------------------------------------------------------------------------

extern "C" void kernel_launch(void* const* d_in, const int* in_sizes, int n_in,
                              void* d_out, int out_size, void* d_ws, size_t ws_size,
                              hipStream_t stream) {
    const float* x  = (const float*)d_in[0];
    const int*   ei = (const int*)  d_in[1];
    const float* W1 = (const float*)d_in[2];
    const float* b1 = (const float*)d_in[3];
    const float* W2 = (const float*)d_in[4];
    const float* b2 = (const float*)d_in[5];
    const float* W3 = (const float*)d_in[6];
    const float* b3 = (const float*)d_in[7];
    const float* W4 = (const float*)d_in[8];
    const float* b4 = (const float*)d_in[9];

    const int N = N_NODES, E = N_EDGES;
    const int NSB = (N + 1023) / 1024;

    char* p = (char*)d_ws;
    auto carve = [&](size_t bytes) {
        char* q = p;
        p += (bytes + 255) & ~(size_t)255;
        return (void*)q;
    };
    int*      deg      = (int*)     carve((size_t)N * 4);
    int*      offsets  = (int*)     carve((size_t)(N + 1) * 4);
    int*      csr_src  = (int*)     carve((size_t)E * 4);
    float*    dinv     = (float*)   carve((size_t)N * 4);
    int*      blocksum = (int*)     carve((size_t)NSB * 4);
    int*      blockoff = (int*)     carve((size_t)NSB * 4);
    int*      gcur     = (int*)     carve((size_t)NBUK * 4);
    unsigned* arena    = (unsigned*)carve((size_t)NBUK * BCAP * 4);
    __half2*  A        = (__half2*) carve((size_t)N * 128 * 2);   // fp16 chunk-major
    float*    B        = (float*)   carve((size_t)N * 128 * 4);   // fp32 row-major

    // ---- graph build ----
    hipMemsetAsync(gcur, 0, (size_t)NBUK * 4, stream);
    p0_bucket<<<512, 256, 0, stream>>>(ei, gcur, arena, E);
    p1_count<<<NBUK, 256, 0, stream>>>(arena, gcur, deg, dinv, N);
    scan_blocksum<<<NSB, 256, 0, stream>>>(deg, blocksum, N);
    scan_blockoff<<<1, 64, 0, stream>>>(blocksum, blockoff, NSB, offsets, N, E);
    scan_fill<<<NSB, 256, 0, stream>>>(deg, blockoff, offsets, N);
    p2_fill<<<NBUK, 256, 0, stream>>>(arena, gcur, offsets, csr_src, N);

    // ---- layers ----
    const int gemm_grid = (N + 63) / 64;          // 782
    dim3 agg128_grid(N / 4, 4);                   // 12500 x 4 chunks
    dim3 agg64_grid(N / 4, 2);                    // 12500 x 2 chunks

    gemm_scale_kernel<128><<<gemm_grid, 256, 0, stream>>>(x, W1, dinv, A, N);
    agg_chunk_kernel<true, 64><<<agg128_grid, 256, 0, stream>>>(A, offsets, csr_src, dinv, b1, B, N);
    gemm_scale_kernel<128><<<gemm_grid, 256, 0, stream>>>(B, W2, dinv, A, N);
    agg_chunk_kernel<true, 64><<<agg128_grid, 256, 0, stream>>>(A, offsets, csr_src, dinv, b2, B, N);
    gemm_scale_kernel<128><<<gemm_grid, 256, 0, stream>>>(B, W3, dinv, A, N);
    agg_chunk_kernel<true, 64><<<agg128_grid, 256, 0, stream>>>(A, offsets, csr_src, dinv, b3, B, N);
    gemm_scale_kernel<64><<<gemm_grid, 128, 0, stream>>>(B, W4, dinv, A, N);
    agg_chunk_kernel<false, 32><<<agg64_grid, 256, 0, stream>>>(A, offsets, csr_src, dinv, b4, (float*)d_out, N);
}

// Round 7
// 402.430 us; speedup vs baseline: 1.5319x; 1.3718x over previous
//
#include <hip/hip_runtime.h>
#include <hip/hip_fp16.h>
#include <type_traits>

#define N_NODES 50000
#define N_EDGES 800000
#define WIN_BITS 9
#define WIN 512
#define NBUK ((N_NODES + WIN - 1) / WIN)   // 98
#define BCAP 16384

// ---------------------------------------------------------------------------
// P0: bucket edges by destination window. Packed entry: (src << 9) | (dst & 511)
// ---------------------------------------------------------------------------
__global__ __launch_bounds__(256) void p0_bucket(const int* __restrict__ ei,
                                                 int* __restrict__ gcur,
                                                 unsigned* __restrict__ arena, int E) {
    __shared__ int lcnt[NBUK];
    __shared__ int lbase[NBUK];
    int tid = threadIdx.x;
    int chunk = (E + gridDim.x - 1) / gridDim.x;
    int e0 = blockIdx.x * chunk;
    int e1 = e0 + chunk; if (e1 > E) e1 = E;
    for (int b = tid; b < NBUK; b += 256) lcnt[b] = 0;
    __syncthreads();
    for (int e = e0 + tid; e < e1; e += 256) {
        int dst = ei[E + e];
        atomicAdd(&lcnt[dst >> WIN_BITS], 1);
    }
    __syncthreads();
    for (int b = tid; b < NBUK; b += 256) {
        lbase[b] = atomicAdd(&gcur[b], lcnt[b]);
        lcnt[b] = 0;
    }
    __syncthreads();
    for (int e = e0 + tid; e < e1; e += 256) {
        int dst = ei[E + e];
        int src = ei[e];
        int b = dst >> WIN_BITS;
        int pos = lbase[b] + atomicAdd(&lcnt[b], 1);
        if (pos < BCAP)
            arena[(size_t)b * BCAP + pos] = ((unsigned)src << WIN_BITS) | (unsigned)(dst & (WIN - 1));
    }
}

// ---------------------------------------------------------------------------
// P1: per-bucket degree count (LDS histogram) + dinv.
// ---------------------------------------------------------------------------
__global__ __launch_bounds__(256) void p1_count(const unsigned* __restrict__ arena,
                                                const int* __restrict__ gcur,
                                                int* __restrict__ deg,
                                                float* __restrict__ dinv, int n) {
    __shared__ int cnt[WIN];
    int b = blockIdx.x, tid = threadIdx.x;
    for (int j = tid; j < WIN; j += 256) cnt[j] = 0;
    __syncthreads();
    int m = gcur[b]; if (m > BCAP) m = BCAP;
    const unsigned* a = arena + (size_t)b * BCAP;
    for (int i = tid; i < m; i += 256) atomicAdd(&cnt[a[i] & (WIN - 1)], 1);
    __syncthreads();
    int base = b << WIN_BITS;
    for (int j = tid; j < WIN; j += 256) {
        int d = base + j;
        if (d < n) {
            int c = cnt[j];
            deg[d] = c;
            dinv[d] = rsqrtf((float)(c + 1));
        }
    }
}

// ---------------------------------------------------------------------------
// Scan (3-phase)
// ---------------------------------------------------------------------------
__global__ __launch_bounds__(256) void scan_blocksum(const int* __restrict__ deg,
                                                     int* __restrict__ blocksum, int n) {
    int tid = threadIdx.x;
    int i0 = blockIdx.x * 1024 + tid * 4;
    int4 d = make_int4(0, 0, 0, 0);
    if (i0 + 3 < n) d = *(const int4*)&deg[i0];
    else {
        if (i0 < n)     d.x = deg[i0];
        if (i0 + 1 < n) d.y = deg[i0 + 1];
        if (i0 + 2 < n) d.z = deg[i0 + 2];
        if (i0 + 3 < n) d.w = deg[i0 + 3];
    }
    int s = d.x + d.y + d.z + d.w;
    #pragma unroll
    for (int off = 1; off < 64; off <<= 1) s += __shfl_xor(s, off);
    __shared__ int ws[4];
    if ((tid & 63) == 0) ws[tid >> 6] = s;
    __syncthreads();
    if (tid == 0) blocksum[blockIdx.x] = ws[0] + ws[1] + ws[2] + ws[3];
}

__global__ void scan_blockoff(const int* __restrict__ blocksum, int* __restrict__ blockoff,
                              int nb, int* __restrict__ offsets, int n, int total) {
    int lane = threadIdx.x;
    int v = (lane < nb) ? blocksum[lane] : 0;
    int orig = v;
    #pragma unroll
    for (int off = 1; off < 64; off <<= 1) {
        int t = __shfl_up(v, off);
        if (lane >= off) v += t;
    }
    if (lane < nb) blockoff[lane] = v - orig;
    if (lane == 0) offsets[n] = total;
}

__global__ __launch_bounds__(256) void scan_fill(const int* __restrict__ deg,
                                                 const int* __restrict__ blockoff,
                                                 int* __restrict__ offsets, int n) {
    int tid = threadIdx.x;
    int i0 = blockIdx.x * 1024 + tid * 4;
    int4 d = make_int4(0, 0, 0, 0);
    if (i0 + 3 < n) d = *(const int4*)&deg[i0];
    else {
        if (i0 < n)     d.x = deg[i0];
        if (i0 + 1 < n) d.y = deg[i0 + 1];
        if (i0 + 2 < n) d.z = deg[i0 + 2];
        if (i0 + 3 < n) d.w = deg[i0 + 3];
    }
    int ts = d.x + d.y + d.z + d.w;
    __shared__ int sbuf[256];
    sbuf[tid] = ts;
    __syncthreads();
    #pragma unroll
    for (int off = 1; off < 256; off <<= 1) {
        int t = (tid >= off) ? sbuf[tid - off] : 0;
        __syncthreads();
        sbuf[tid] += t;
        __syncthreads();
    }
    int base = blockoff[blockIdx.x] + (sbuf[tid] - ts);
    int o0 = base, o1 = o0 + d.x, o2 = o1 + d.y, o3 = o2 + d.z;
    if (i0 + 3 < n) {
        *(int4*)&offsets[i0] = make_int4(o0, o1, o2, o3);
    } else {
        if (i0 < n)     offsets[i0]     = o0;
        if (i0 + 1 < n) offsets[i0 + 1] = o1;
        if (i0 + 2 < n) offsets[i0 + 2] = o2;
    }
}

// ---------------------------------------------------------------------------
// P2: per-bucket CSR fill.
// ---------------------------------------------------------------------------
__global__ __launch_bounds__(256) void p2_fill(const unsigned* __restrict__ arena,
                                               const int* __restrict__ gcur,
                                               const int* __restrict__ offsets,
                                               int* __restrict__ csr_src, int n) {
    __shared__ int cur[WIN];
    int b = blockIdx.x, tid = threadIdx.x;
    int base = b << WIN_BITS;
    for (int j = tid; j < WIN; j += 256) {
        int d = base + j;
        cur[j] = (d < n) ? offsets[d] : 0;
    }
    __syncthreads();
    int m = gcur[b]; if (m > BCAP) m = BCAP;
    const unsigned* a = arena + (size_t)b * BCAP;
    for (int i = tid; i < m; i += 256) {
        unsigned e = a[i];
        int pos = atomicAdd(&cur[e & (WIN - 1)], 1);
        csr_src[pos] = (int)(e >> WIN_BITS);
    }
}

// ---------------------------------------------------------------------------
// GEMM: h[i][j] = fp16( (x[i,:] @ W[:,j]) * dinv[i] ), row-major fp16 out.
// Input templated: float (layer 1) or __half (layers 2-4).
// Thread tile 4 rows x 8 cols; 64 rows/block -> grid 782 (~3-5 blocks/CU).
// Split-K LDS staging (64 k-rows). Slot swizzle -> 2-way LDS conflicts (free).
// ---------------------------------------------------------------------------
template<typename InT>
__device__ inline float4 ld4(const InT* p) {
    if constexpr (std::is_same_v<InT, float>) {
        return *(const float4*)p;
    } else {
        uint2 u = *(const uint2*)p;          // 4 halfs
        float2 fa = __half22float2(*(__half2*)&u.x);
        float2 fb = __half22float2(*(__half2*)&u.y);
        return make_float4(fa.x, fa.y, fb.x, fb.y);
    }
}

template<int FO, typename InT>
__global__ __launch_bounds__(16 * (FO / 8)) void gemm_scale_kernel(
        const InT* __restrict__ x, const float* __restrict__ W,
        const float* __restrict__ dinv, __half* __restrict__ h, int n) {
    constexpr int TC      = FO / 8;       // col groups: 16 (FO=128) / 8 (FO=64)
    constexpr int THREADS = TC * 16;      // 256 / 128
    constexpr int F4      = FO / 4;
    constexpr int HALF    = F4 / 2;

    __shared__ float w_lds[64 * FO];      // 32 KB / 16 KB
    int tid = threadIdx.x;
    int tc = tid % TC, tr = tid / TC;     // tr in [0,16)
    int row0 = blockIdx.x * 64 + tr * 4;

    const InT* xp[4];
    #pragma unroll
    for (int r = 0; r < 4; ++r) {
        int rowc = row0 + r; if (rowc > n - 1) rowc = n - 1;   // clamp: safe reads
        xp[r] = x + (size_t)rowc * 128;
    }

    float acc[4][8];
    #pragma unroll
    for (int r = 0; r < 4; ++r)
        #pragma unroll
        for (int c = 0; c < 8; ++c) acc[r][c] = 0.0f;

    #pragma unroll
    for (int stage = 0; stage < 2; ++stage) {
        int ks = stage << 6;
        if (stage) __syncthreads();
        for (int i = tid; i < 64 * F4; i += THREADS) {
            int r = i / F4, jf4 = i % F4;
            int phys = (jf4 & 1) * HALF + (jf4 >> 1);
            float4 v = *(const float4*)&W[(size_t)(ks + r) * FO + jf4 * 4];
            *(float4*)&w_lds[(size_t)r * FO + phys * 4] = v;
        }
        __syncthreads();

        float4 xb[4];
        #pragma unroll
        for (int r = 0; r < 4; ++r) xb[r] = ld4(&xp[r][ks]);

        for (int kk = 0; kk < 64; kk += 4) {
            float4 xc[4];
            #pragma unroll
            for (int r = 0; r < 4; ++r) xc[r] = xb[r];
            if (kk + 4 < 64) {
                #pragma unroll
                for (int r = 0; r < 4; ++r) xb[r] = ld4(&xp[r][ks + kk + 4]);
            }
            #pragma unroll
            for (int dk = 0; dk < 4; ++dk) {
                float w[8];
                *(float4*)&w[0] = *(const float4*)&w_lds[(size_t)(kk + dk) * FO + tc * 4];
                *(float4*)&w[4] = *(const float4*)&w_lds[(size_t)(kk + dk) * FO + (HALF + tc) * 4];
                #pragma unroll
                for (int r = 0; r < 4; ++r) {
                    float xs = (&xc[r].x)[dk];
                    #pragma unroll
                    for (int c = 0; c < 8; ++c)
                        acc[r][c] = fmaf(xs, w[c], acc[r][c]);
                }
            }
        }
    }

    // epilogue: row-major fp16, thread covers cols [tc*8, tc*8+8)
    #pragma unroll
    for (int r = 0; r < 4; ++r) {
        int row = row0 + r;
        if (row < n) {
            float d = dinv[row];
            __half2 hv[4];
            #pragma unroll
            for (int q = 0; q < 4; ++q)
                hv[q] = __float22half2_rn(make_float2(acc[r][2 * q] * d, acc[r][2 * q + 1] * d));
            *(uint4*)&h[(size_t)row * FO + tc * 8] = *(const uint4*)hv;
        }
    }
}

// ---------------------------------------------------------------------------
// Aggregation (flat, R4-proven): out[c] = dinv[c]*(h[c] + sum h[src]) + b.
// One 64-lane wave per node (4 nodes / 256-thr block). Full 256-B row gather
// per edge (lane = half2), scalar edge indices, 4 edges in flight.
// OutT = __half (intermediate layers) or float.
// ---------------------------------------------------------------------------
template<typename OutT, bool RELU>
__global__ __launch_bounds__(256) void agg128_kernel(
        const __half2* __restrict__ h2, const int* __restrict__ offsets,
        const int* __restrict__ csr_src, const float* __restrict__ dinv,
        const float* __restrict__ bias, OutT* __restrict__ out, int n) {
    int lane = threadIdx.x & 63;
    int c = (blockIdx.x << 2) + (threadIdx.x >> 6);
    if (c >= n) return;
    c = __builtin_amdgcn_readfirstlane(c);
    float2 acc = __half22float2(h2[(size_t)c * 64 + lane]);   // self loop
    int s = offsets[c], e = offsets[c + 1];
    int i = s;
    for (; i + 3 < e; i += 4) {
        int s0 = csr_src[i], s1 = csr_src[i + 1], s2 = csr_src[i + 2], s3 = csr_src[i + 3];
        float2 f0 = __half22float2(h2[(size_t)s0 * 64 + lane]);
        float2 f1 = __half22float2(h2[(size_t)s1 * 64 + lane]);
        float2 f2 = __half22float2(h2[(size_t)s2 * 64 + lane]);
        float2 f3 = __half22float2(h2[(size_t)s3 * 64 + lane]);
        acc.x += f0.x + f1.x; acc.y += f0.y + f1.y;
        acc.x += f2.x + f3.x; acc.y += f2.y + f3.y;
    }
    for (; i < e; ++i) {
        float2 f = __half22float2(h2[(size_t)csr_src[i] * 64 + lane]);
        acc.x += f.x; acc.y += f.y;
    }
    float dc = dinv[c];
    float2 bb = ((const float2*)bias)[lane];
    float vx = fmaf(acc.x, dc, bb.x);
    float vy = fmaf(acc.y, dc, bb.y);
    if (RELU) { vx = fmaxf(vx, 0.0f); vy = fmaxf(vy, 0.0f); }
    if constexpr (std::is_same_v<OutT, __half>) {
        ((__half2*)out)[(size_t)c * 64 + lane] = __float22half2_rn(make_float2(vx, vy));
    } else {
        float2 o; o.x = vx; o.y = vy;
        ((float2*)out)[(size_t)c * 64 + lane] = o;
    }
}

// Final layer (FO=64): wave = 2 halves x 32 lanes; each half gathers one
// edge's 128-B row (lane = half2); xor-32 reduce; half 0 writes fp32 d_out.
__global__ __launch_bounds__(256) void agg64_kernel(
        const __half2* __restrict__ h2, const int* __restrict__ offsets,
        const int* __restrict__ csr_src, const float* __restrict__ dinv,
        const float* __restrict__ bias, float* __restrict__ out, int n) {
    int lane = threadIdx.x & 63;
    int hf = lane >> 5, sl = lane & 31;
    int c = (blockIdx.x << 2) + (threadIdx.x >> 6);
    if (c >= n) return;
    c = __builtin_amdgcn_readfirstlane(c);
    float2 acc = make_float2(0.0f, 0.0f);
    if (hf == 0) acc = __half22float2(h2[(size_t)c * 32 + sl]);   // self loop
    int s = offsets[c], e = offsets[c + 1];
    int i = s;
    for (; i + 3 < e; i += 4) {
        int sa = csr_src[i + hf];
        int sb = csr_src[i + 2 + hf];
        float2 fa = __half22float2(h2[(size_t)sa * 32 + sl]);
        float2 fb = __half22float2(h2[(size_t)sb * 32 + sl]);
        acc.x += fa.x + fb.x; acc.y += fa.y + fb.y;
    }
    for (; i + 1 < e; i += 2) {
        int sa = csr_src[i + hf];
        float2 fa = __half22float2(h2[(size_t)sa * 32 + sl]);
        acc.x += fa.x; acc.y += fa.y;
    }
    if (i < e && hf == 0) {
        float2 fa = __half22float2(h2[(size_t)csr_src[i] * 32 + sl]);
        acc.x += fa.x; acc.y += fa.y;
    }
    acc.x += __shfl_xor(acc.x, 32);
    acc.y += __shfl_xor(acc.y, 32);
    if (hf == 0) {
        float dc = dinv[c];
        float2 bb = ((const float2*)bias)[sl];
        float2 o;
        o.x = fmaf(acc.x, dc, bb.x);
        o.y = fmaf(acc.y, dc, bb.y);
        ((float2*)out)[(size_t)c * 32 + sl] = o;
    }
}

// ---------------------------------------------------------------------------

extern "C" void kernel_launch(void* const* d_in, const int* in_sizes, int n_in,
                              void* d_out, int out_size, void* d_ws, size_t ws_size,
                              hipStream_t stream) {
    const float* x  = (const float*)d_in[0];
    const int*   ei = (const int*)  d_in[1];
    const float* W1 = (const float*)d_in[2];
    const float* b1 = (const float*)d_in[3];
    const float* W2 = (const float*)d_in[4];
    const float* b2 = (const float*)d_in[5];
    const float* W3 = (const float*)d_in[6];
    const float* b3 = (const float*)d_in[7];
    const float* W4 = (const float*)d_in[8];
    const float* b4 = (const float*)d_in[9];

    const int N = N_NODES, E = N_EDGES;
    const int NSB = (N + 1023) / 1024;

    char* p = (char*)d_ws;
    auto carve = [&](size_t bytes) {
        char* q = p;
        p += (bytes + 255) & ~(size_t)255;
        return (void*)q;
    };
    int*      deg      = (int*)     carve((size_t)N * 4);
    int*      offsets  = (int*)     carve((size_t)(N + 1) * 4);
    int*      csr_src  = (int*)     carve((size_t)E * 4);
    float*    dinv     = (float*)   carve((size_t)N * 4);
    int*      blocksum = (int*)     carve((size_t)NSB * 4);
    int*      blockoff = (int*)     carve((size_t)NSB * 4);
    int*      gcur     = (int*)     carve((size_t)NBUK * 4);
    unsigned* arena    = (unsigned*)carve((size_t)NBUK * BCAP * 4);
    __half*   A        = (__half*)  carve((size_t)N * 128 * 2);   // gemm out, fp16
    __half*   B        = (__half*)  carve((size_t)N * 128 * 2);   // agg out, fp16

    // ---- graph build ----
    hipMemsetAsync(gcur, 0, (size_t)NBUK * 4, stream);
    p0_bucket<<<512, 256, 0, stream>>>(ei, gcur, arena, E);
    p1_count<<<NBUK, 256, 0, stream>>>(arena, gcur, deg, dinv, N);
    scan_blocksum<<<NSB, 256, 0, stream>>>(deg, blocksum, N);
    scan_blockoff<<<1, 64, 0, stream>>>(blocksum, blockoff, NSB, offsets, N, E);
    scan_fill<<<NSB, 256, 0, stream>>>(deg, blockoff, offsets, N);
    p2_fill<<<NBUK, 256, 0, stream>>>(arena, gcur, offsets, csr_src, N);

    // ---- layers ----
    const int gemm_grid = (N + 63) / 64;    // 782
    const int agg_grid  = (N + 3) / 4;      // 12500

    gemm_scale_kernel<128, float><<<gemm_grid, 256, 0, stream>>>(x, W1, dinv, A, N);
    agg128_kernel<__half, true><<<agg_grid, 256, 0, stream>>>((const __half2*)A, offsets, csr_src, dinv, b1, B, N);
    gemm_scale_kernel<128, __half><<<gemm_grid, 256, 0, stream>>>(B, W2, dinv, A, N);
    agg128_kernel<__half, true><<<agg_grid, 256, 0, stream>>>((const __half2*)A, offsets, csr_src, dinv, b2, B, N);
    gemm_scale_kernel<128, __half><<<gemm_grid, 256, 0, stream>>>(B, W3, dinv, A, N);
    agg128_kernel<__half, true><<<agg_grid, 256, 0, stream>>>((const __half2*)A, offsets, csr_src, dinv, b3, B, N);
    gemm_scale_kernel<64, __half><<<gemm_grid, 128, 0, stream>>>(B, W4, dinv, A, N);
    agg64_kernel<<<agg_grid, 256, 0, stream>>>((const __half2*)A, offsets, csr_src, dinv, b4, (float*)d_out, N);
}

// Round 8
// 312.781 us; speedup vs baseline: 1.9710x; 1.2866x over previous
//
#include <hip/hip_runtime.h>
#include <hip/hip_fp16.h>
#include <type_traits>

#define N_NODES 50000
#define N_EDGES 800000
#define WIN_BITS 9
#define WIN 512
#define NBUK ((N_NODES + WIN - 1) / WIN)   // 98
#define BCAP 16384

typedef _Float16 half8 __attribute__((ext_vector_type(8)));
typedef float floatx4 __attribute__((ext_vector_type(4)));

// ---------------------------------------------------------------------------
// P0: bucket edges by destination window. Packed entry: (src << 9) | (dst & 511)
// ---------------------------------------------------------------------------
__global__ __launch_bounds__(256) void p0_bucket(const int* __restrict__ ei,
                                                 int* __restrict__ gcur,
                                                 unsigned* __restrict__ arena, int E) {
    __shared__ int lcnt[NBUK];
    __shared__ int lbase[NBUK];
    int tid = threadIdx.x;
    int chunk = (E + gridDim.x - 1) / gridDim.x;
    int e0 = blockIdx.x * chunk;
    int e1 = e0 + chunk; if (e1 > E) e1 = E;
    for (int b = tid; b < NBUK; b += 256) lcnt[b] = 0;
    __syncthreads();
    for (int e = e0 + tid; e < e1; e += 256) {
        int dst = ei[E + e];
        atomicAdd(&lcnt[dst >> WIN_BITS], 1);
    }
    __syncthreads();
    for (int b = tid; b < NBUK; b += 256) {
        lbase[b] = atomicAdd(&gcur[b], lcnt[b]);
        lcnt[b] = 0;
    }
    __syncthreads();
    for (int e = e0 + tid; e < e1; e += 256) {
        int dst = ei[E + e];
        int src = ei[e];
        int b = dst >> WIN_BITS;
        int pos = lbase[b] + atomicAdd(&lcnt[b], 1);
        if (pos < BCAP)
            arena[(size_t)b * BCAP + pos] = ((unsigned)src << WIN_BITS) | (unsigned)(dst & (WIN - 1));
    }
}

// ---------------------------------------------------------------------------
// P1: per-bucket degree count (LDS histogram) + dinv.
// ---------------------------------------------------------------------------
__global__ __launch_bounds__(256) void p1_count(const unsigned* __restrict__ arena,
                                                const int* __restrict__ gcur,
                                                int* __restrict__ deg,
                                                float* __restrict__ dinv, int n) {
    __shared__ int cnt[WIN];
    int b = blockIdx.x, tid = threadIdx.x;
    for (int j = tid; j < WIN; j += 256) cnt[j] = 0;
    __syncthreads();
    int m = gcur[b]; if (m > BCAP) m = BCAP;
    const unsigned* a = arena + (size_t)b * BCAP;
    for (int i = tid; i < m; i += 256) atomicAdd(&cnt[a[i] & (WIN - 1)], 1);
    __syncthreads();
    int base = b << WIN_BITS;
    for (int j = tid; j < WIN; j += 256) {
        int d = base + j;
        if (d < n) {
            int c = cnt[j];
            deg[d] = c;
            dinv[d] = rsqrtf((float)(c + 1));
        }
    }
}

// ---------------------------------------------------------------------------
// Scan (3-phase)
// ---------------------------------------------------------------------------
__global__ __launch_bounds__(256) void scan_blocksum(const int* __restrict__ deg,
                                                     int* __restrict__ blocksum, int n) {
    int tid = threadIdx.x;
    int i0 = blockIdx.x * 1024 + tid * 4;
    int4 d = make_int4(0, 0, 0, 0);
    if (i0 + 3 < n) d = *(const int4*)&deg[i0];
    else {
        if (i0 < n)     d.x = deg[i0];
        if (i0 + 1 < n) d.y = deg[i0 + 1];
        if (i0 + 2 < n) d.z = deg[i0 + 2];
        if (i0 + 3 < n) d.w = deg[i0 + 3];
    }
    int s = d.x + d.y + d.z + d.w;
    #pragma unroll
    for (int off = 1; off < 64; off <<= 1) s += __shfl_xor(s, off);
    __shared__ int ws[4];
    if ((tid & 63) == 0) ws[tid >> 6] = s;
    __syncthreads();
    if (tid == 0) blocksum[blockIdx.x] = ws[0] + ws[1] + ws[2] + ws[3];
}

__global__ void scan_blockoff(const int* __restrict__ blocksum, int* __restrict__ blockoff,
                              int nb, int* __restrict__ offsets, int n, int total) {
    int lane = threadIdx.x;
    int v = (lane < nb) ? blocksum[lane] : 0;
    int orig = v;
    #pragma unroll
    for (int off = 1; off < 64; off <<= 1) {
        int t = __shfl_up(v, off);
        if (lane >= off) v += t;
    }
    if (lane < nb) blockoff[lane] = v - orig;
    if (lane == 0) offsets[n] = total;
}

__global__ __launch_bounds__(256) void scan_fill(const int* __restrict__ deg,
                                                 const int* __restrict__ blockoff,
                                                 int* __restrict__ offsets, int n) {
    int tid = threadIdx.x;
    int i0 = blockIdx.x * 1024 + tid * 4;
    int4 d = make_int4(0, 0, 0, 0);
    if (i0 + 3 < n) d = *(const int4*)&deg[i0];
    else {
        if (i0 < n)     d.x = deg[i0];
        if (i0 + 1 < n) d.y = deg[i0 + 1];
        if (i0 + 2 < n) d.z = deg[i0 + 2];
        if (i0 + 3 < n) d.w = deg[i0 + 3];
    }
    int ts = d.x + d.y + d.z + d.w;
    __shared__ int sbuf[256];
    sbuf[tid] = ts;
    __syncthreads();
    #pragma unroll
    for (int off = 1; off < 256; off <<= 1) {
        int t = (tid >= off) ? sbuf[tid - off] : 0;
        __syncthreads();
        sbuf[tid] += t;
        __syncthreads();
    }
    int base = blockoff[blockIdx.x] + (sbuf[tid] - ts);
    int o0 = base, o1 = o0 + d.x, o2 = o1 + d.y, o3 = o2 + d.z;
    if (i0 + 3 < n) {
        *(int4*)&offsets[i0] = make_int4(o0, o1, o2, o3);
    } else {
        if (i0 < n)     offsets[i0]     = o0;
        if (i0 + 1 < n) offsets[i0 + 1] = o1;
        if (i0 + 2 < n) offsets[i0 + 2] = o2;
    }
}

// ---------------------------------------------------------------------------
// P2: per-bucket CSR fill.
// ---------------------------------------------------------------------------
__global__ __launch_bounds__(256) void p2_fill(const unsigned* __restrict__ arena,
                                               const int* __restrict__ gcur,
                                               const int* __restrict__ offsets,
                                               int* __restrict__ csr_src, int n) {
    __shared__ int cur[WIN];
    int b = blockIdx.x, tid = threadIdx.x;
    int base = b << WIN_BITS;
    for (int j = tid; j < WIN; j += 256) {
        int d = base + j;
        cur[j] = (d < n) ? offsets[d] : 0;
    }
    __syncthreads();
    int m = gcur[b]; if (m > BCAP) m = BCAP;
    const unsigned* a = arena + (size_t)b * BCAP;
    for (int i = tid; i < m; i += 256) {
        unsigned e = a[i];
        int pos = atomicAdd(&cur[e & (WIN - 1)], 1);
        csr_src[pos] = (int)(e >> WIN_BITS);
    }
}

// ---------------------------------------------------------------------------
// MFMA GEMM: h[i][j] = fp16( (x[i,:] @ W[:,j]) * dinv[i] ), FI=128.
// mfma_f32_16x16x32_f16 with swapped operands: A-frag = W-tile (m = outcol),
// B-frag = x-tile (n = node). D: row(q*4+reg) = outcol-in-tile, col(lane&15)
// = node-in-tile -> each lane holds 4 consecutive outcols of ONE node ->
// packed 8-B stores, one dinv load per lane.
// Block: 256 thr = 4 waves, 64 nodes (wave = 16 nodes). Prologue stages W
// (fp32 -> fp16) into LDS in fragment order: group (s,q,col) holds
// W[s*32+q*8 .. +8][col], 16 B contiguous per lane on read.
// ---------------------------------------------------------------------------
template<int FO, typename InT>
__global__ __launch_bounds__(256) void gemm_mfma_kernel(
        const InT* __restrict__ x, const float* __restrict__ W,
        const float* __restrict__ dinv, __half* __restrict__ h, int n) {
    constexpr int NT = FO / 16;                 // col tiles: 8 or 4
    __shared__ _Float16 wlds[4 * 4 * FO * 8];   // 32 KB (FO=128) / 16 KB

    int tid = threadIdx.x;
    // ---- prologue: stage W in fragment order ----
    constexpr int G = 4 * 4 * FO;               // groups of 8 halfs
    for (int it = 0; it < G / 256; ++it) {
        int g = tid + it * 256;
        int col = g % FO;
        int sq = g / FO;                        // s*4 + q
        int k0 = sq * 8;                        // s*32 + q*8
        half8 hv;
        #pragma unroll
        for (int j = 0; j < 8; ++j)
            hv[j] = (_Float16)W[(size_t)(k0 + j) * FO + col];
        *(half8*)&wlds[(size_t)g * 8] = hv;
    }
    __syncthreads();

    int ln = tid & 15;
    int q  = (tid >> 4) & 3;
    int w  = tid >> 6;
    int node = blockIdx.x * 64 + w * 16 + ln;
    int nodec = node < n ? node : n - 1;        // clamped for loads
    const InT* xrow = x + (size_t)nodec * 128;

    floatx4 acc[NT];
    #pragma unroll
    for (int t = 0; t < NT; ++t) acc[t] = (floatx4){0.f, 0.f, 0.f, 0.f};

    #pragma unroll
    for (int s = 0; s < 4; ++s) {
        // B-frag (x): 8 contiguous k at k = s*32 + q*8
        half8 xf;
        if constexpr (std::is_same_v<InT, float>) {
            const float* xp = xrow + s * 32 + q * 8;
            float4 a0 = *(const float4*)xp;
            float4 a1 = *(const float4*)(xp + 4);
            xf[0] = (_Float16)a0.x; xf[1] = (_Float16)a0.y;
            xf[2] = (_Float16)a0.z; xf[3] = (_Float16)a0.w;
            xf[4] = (_Float16)a1.x; xf[5] = (_Float16)a1.y;
            xf[6] = (_Float16)a1.z; xf[7] = (_Float16)a1.w;
        } else {
            xf = *(const half8*)(xrow + s * 32 + q * 8);
        }
        int sq = s * 4 + q;
        #pragma unroll
        for (int t = 0; t < NT; ++t) {
            half8 wf = *(const half8*)&wlds[(size_t)(sq * FO + t * 16 + ln) * 8];
            acc[t] = __builtin_amdgcn_mfma_f32_16x16x32_f16(wf, xf, acc[t], 0, 0, 0);
        }
    }

    if (node < n) {
        float dv = dinv[node];
        __half* hrow = h + (size_t)node * FO;
        #pragma unroll
        for (int t = 0; t < NT; ++t) {
            __half2 p[2];
            p[0] = __float22half2_rn(make_float2(acc[t][0] * dv, acc[t][1] * dv));
            p[1] = __float22half2_rn(make_float2(acc[t][2] * dv, acc[t][3] * dv));
            *(uint2*)&hrow[t * 16 + q * 4] = *(const uint2*)p;
        }
    }
}

// ---------------------------------------------------------------------------
// Aggregation (flat): out[c] = dinv[c]*(h[c] + sum h[src]) + b.
// One 64-lane wave per node; 256-B row gather per edge; scalar indices.
// ---------------------------------------------------------------------------
template<typename OutT, bool RELU>
__global__ __launch_bounds__(256) void agg128_kernel(
        const __half2* __restrict__ h2, const int* __restrict__ offsets,
        const int* __restrict__ csr_src, const float* __restrict__ dinv,
        const float* __restrict__ bias, OutT* __restrict__ out, int n) {
    int lane = threadIdx.x & 63;
    int c = (blockIdx.x << 2) + (threadIdx.x >> 6);
    if (c >= n) return;
    c = __builtin_amdgcn_readfirstlane(c);
    float2 acc = __half22float2(h2[(size_t)c * 64 + lane]);   // self loop
    int s = offsets[c], e = offsets[c + 1];
    int i = s;
    for (; i + 3 < e; i += 4) {
        int s0 = csr_src[i], s1 = csr_src[i + 1], s2 = csr_src[i + 2], s3 = csr_src[i + 3];
        float2 f0 = __half22float2(h2[(size_t)s0 * 64 + lane]);
        float2 f1 = __half22float2(h2[(size_t)s1 * 64 + lane]);
        float2 f2 = __half22float2(h2[(size_t)s2 * 64 + lane]);
        float2 f3 = __half22float2(h2[(size_t)s3 * 64 + lane]);
        acc.x += f0.x + f1.x; acc.y += f0.y + f1.y;
        acc.x += f2.x + f3.x; acc.y += f2.y + f3.y;
    }
    for (; i < e; ++i) {
        float2 f = __half22float2(h2[(size_t)csr_src[i] * 64 + lane]);
        acc.x += f.x; acc.y += f.y;
    }
    float dc = dinv[c];
    float2 bb = ((const float2*)bias)[lane];
    float vx = fmaf(acc.x, dc, bb.x);
    float vy = fmaf(acc.y, dc, bb.y);
    if (RELU) { vx = fmaxf(vx, 0.0f); vy = fmaxf(vy, 0.0f); }
    if constexpr (std::is_same_v<OutT, __half>) {
        ((__half2*)out)[(size_t)c * 64 + lane] = __float22half2_rn(make_float2(vx, vy));
    } else {
        float2 o; o.x = vx; o.y = vy;
        ((float2*)out)[(size_t)c * 64 + lane] = o;
    }
}

// Final layer (FO=64): wave = 2 halves x 32 lanes; 128-B row gather per edge.
__global__ __launch_bounds__(256) void agg64_kernel(
        const __half2* __restrict__ h2, const int* __restrict__ offsets,
        const int* __restrict__ csr_src, const float* __restrict__ dinv,
        const float* __restrict__ bias, float* __restrict__ out, int n) {
    int lane = threadIdx.x & 63;
    int hf = lane >> 5, sl = lane & 31;
    int c = (blockIdx.x << 2) + (threadIdx.x >> 6);
    if (c >= n) return;
    c = __builtin_amdgcn_readfirstlane(c);
    float2 acc = make_float2(0.0f, 0.0f);
    if (hf == 0) acc = __half22float2(h2[(size_t)c * 32 + sl]);   // self loop
    int s = offsets[c], e = offsets[c + 1];
    int i = s;
    for (; i + 3 < e; i += 4) {
        int sa = csr_src[i + hf];
        int sb = csr_src[i + 2 + hf];
        float2 fa = __half22float2(h2[(size_t)sa * 32 + sl]);
        float2 fb = __half22float2(h2[(size_t)sb * 32 + sl]);
        acc.x += fa.x + fb.x; acc.y += fa.y + fb.y;
    }
    for (; i + 1 < e; i += 2) {
        int sa = csr_src[i + hf];
        float2 fa = __half22float2(h2[(size_t)sa * 32 + sl]);
        acc.x += fa.x; acc.y += fa.y;
    }
    if (i < e && hf == 0) {
        float2 fa = __half22float2(h2[(size_t)csr_src[i] * 32 + sl]);
        acc.x += fa.x; acc.y += fa.y;
    }
    acc.x += __shfl_xor(acc.x, 32);
    acc.y += __shfl_xor(acc.y, 32);
    if (hf == 0) {
        float dc = dinv[c];
        float2 bb = ((const float2*)bias)[sl];
        float2 o;
        o.x = fmaf(acc.x, dc, bb.x);
        o.y = fmaf(acc.y, dc, bb.y);
        ((float2*)out)[(size_t)c * 32 + sl] = o;
    }
}

// ---------------------------------------------------------------------------

extern "C" void kernel_launch(void* const* d_in, const int* in_sizes, int n_in,
                              void* d_out, int out_size, void* d_ws, size_t ws_size,
                              hipStream_t stream) {
    const float* x  = (const float*)d_in[0];
    const int*   ei = (const int*)  d_in[1];
    const float* W1 = (const float*)d_in[2];
    const float* b1 = (const float*)d_in[3];
    const float* W2 = (const float*)d_in[4];
    const float* b2 = (const float*)d_in[5];
    const float* W3 = (const float*)d_in[6];
    const float* b3 = (const float*)d_in[7];
    const float* W4 = (const float*)d_in[8];
    const float* b4 = (const float*)d_in[9];

    const int N = N_NODES, E = N_EDGES;
    const int NSB = (N + 1023) / 1024;

    char* p = (char*)d_ws;
    auto carve = [&](size_t bytes) {
        char* q = p;
        p += (bytes + 255) & ~(size_t)255;
        return (void*)q;
    };
    int*      deg      = (int*)     carve((size_t)N * 4);
    int*      offsets  = (int*)     carve((size_t)(N + 1) * 4);
    int*      csr_src  = (int*)     carve((size_t)E * 4);
    float*    dinv     = (float*)   carve((size_t)N * 4);
    int*      blocksum = (int*)     carve((size_t)NSB * 4);
    int*      blockoff = (int*)     carve((size_t)NSB * 4);
    int*      gcur     = (int*)     carve((size_t)NBUK * 4);
    unsigned* arena    = (unsigned*)carve((size_t)NBUK * BCAP * 4);
    __half*   A        = (__half*)  carve((size_t)N * 128 * 2);   // gemm out, fp16
    __half*   B        = (__half*)  carve((size_t)N * 128 * 2);   // agg out, fp16

    // ---- graph build ----
    hipMemsetAsync(gcur, 0, (size_t)NBUK * 4, stream);
    p0_bucket<<<512, 256, 0, stream>>>(ei, gcur, arena, E);
    p1_count<<<NBUK, 256, 0, stream>>>(arena, gcur, deg, dinv, N);
    scan_blocksum<<<NSB, 256, 0, stream>>>(deg, blocksum, N);
    scan_blockoff<<<1, 64, 0, stream>>>(blocksum, blockoff, NSB, offsets, N, E);
    scan_fill<<<NSB, 256, 0, stream>>>(deg, blockoff, offsets, N);
    p2_fill<<<NBUK, 256, 0, stream>>>(arena, gcur, offsets, csr_src, N);

    // ---- layers ----
    const int gemm_grid = (N + 63) / 64;    // 782
    const int agg_grid  = (N + 3) / 4;      // 12500

    gemm_mfma_kernel<128, float><<<gemm_grid, 256, 0, stream>>>(x, W1, dinv, A, N);
    agg128_kernel<__half, true><<<agg_grid, 256, 0, stream>>>((const __half2*)A, offsets, csr_src, dinv, b1, B, N);
    gemm_mfma_kernel<128, __half><<<gemm_grid, 256, 0, stream>>>(B, W2, dinv, A, N);
    agg128_kernel<__half, true><<<agg_grid, 256, 0, stream>>>((const __half2*)A, offsets, csr_src, dinv, b2, B, N);
    gemm_mfma_kernel<128, __half><<<gemm_grid, 256, 0, stream>>>(B, W3, dinv, A, N);
    agg128_kernel<__half, true><<<agg_grid, 256, 0, stream>>>((const __half2*)A, offsets, csr_src, dinv, b3, B, N);
    gemm_mfma_kernel<64, __half><<<gemm_grid, 256, 0, stream>>>(B, W4, dinv, A, N);
    agg64_kernel<<<agg_grid, 256, 0, stream>>>((const __half2*)A, offsets, csr_src, dinv, b4, (float*)d_out, N);
}